// Round 5
// baseline (122.934 us; speedup 1.0000x reference)
//
#include <hip/hip_runtime.h>

// R11 = R10 (validated, 118.1 us, dispatch 62.7) re-gridded for occupancy.
// R10 counters: OccupancyPercent 10.8% = ONE 4-wave block per CU; all chain
// LDS/IC latency exposed (VALUBusy 13.5%, HBM idle: steady-state FETCH
// ~0.15 MB — all IC-resident). R11: grid 512 x 256 (2 blocks/CU, 8 waves/CU),
// halving per-thread work in U/chain/out. Same validated data scheme: sc1
// write-once stores + normal cached loads, 8 distinct A-power buffers,
// 2-hop grid barrier (512 arrivals), R10's split FINAL barrier (arrive after
// round-7 drain; t>=128 out-half; complete barrier; t<128 half).
// Chain tiles: 64 rg (4 rows) x 8 cg (32 cols); LDS 43.5 KB (3 blocks/CU
// capacity -> co-residency robust to missing CUs).

#define SEQ_T 256
#define DIM 128
#define ORD 256
#define BMROWS 2048
#define NBLK 512

// float offsets into ws (write-once buffers, guard gaps)
#define OFF_U 0                                  // U[t][bm]: 256*2048
#define OFF_P (OFF_U + SEQ_T * BMROWS)           // P[j][o]: 256*256
#define APSTRIDE (ORD * ORD + 2048)
#define OFF_AP (OFF_P + ORD * ORD + 2048)        // AP[j]=A^(2^(j+1))
#define OFF_FLAGS (OFF_AP + 7 * APSTRIDE + 2048) // 512 flags; gen at +520

#define LD_A(p) \
  __hip_atomic_load((p), __ATOMIC_RELAXED, __HIP_MEMORY_SCOPE_AGENT)
#define ST_A(p, v) \
  __hip_atomic_store((p), (v), __ATOMIC_RELAXED, __HIP_MEMORY_SCOPE_AGENT)

// 2-hop fence-free grid barrier (512 blocks). Correctness from sc1
// write-once buffers + vmcnt drain before arrival (R6-validated scheme).
__device__ __forceinline__ void gbar(unsigned* flags, unsigned* gen,
                                     unsigned target) {
  asm volatile("s_waitcnt vmcnt(0)" ::: "memory");  // drain this wave's sc1 st
  __syncthreads();  // now ALL waves of the block have drained
  const int tid = threadIdx.x;
  if (blockIdx.x == 0) {
    if (tid == 0) ST_A(&flags[0], target);
    while (LD_A(&flags[tid]) < target || LD_A(&flags[tid + 256]) < target)
      __builtin_amdgcn_s_sleep(1);
    __syncthreads();  // all 512 flags seen
    if (tid == 0) ST_A(gen, target);
  } else {
    if (tid == 0) {
      ST_A(&flags[blockIdx.x], target);
      while (LD_A(gen) < target) __builtin_amdgcn_s_sleep(1);
    }
  }
  __syncthreads();
}

__global__ __launch_bounds__(256) void lrmu_all(
    const float* __restrict__ x, const float* __restrict__ K,
    const float* __restrict__ A, const float* __restrict__ Bm,
    float* __restrict__ out, float* __restrict__ ws) {
  __shared__ __align__(16) float Slds[ORD * 32];  // 32 KB: S slice / xs / redo
  __shared__ __align__(16) float lsb[2048];       // 8 KB: left rows / us
  __shared__ __align__(16) float redb[4 * 160];   // 2.5 KB: wave partials
  float* U = ws + OFF_U;
  float* P = ws + OFF_P;
  unsigned* flags = (unsigned*)(ws + OFF_FLAGS);
  unsigned* gen = flags + 520;
  const int blk = blockIdx.x, tid = threadIdx.x;

  // ---------- U phase: U[t][bm] = sum_d x[b][t][d] * K[d][m] ----------
  {
    int b = blk >> 5, tc = blk & 31;  // 8 t-rows per block
    float* xs = Slds;
    for (int idx = tid; idx < 8 * DIM; idx += 256)
      xs[idx] = x[(b * SEQ_T + tc * 8) * DIM + idx];
    __syncthreads();
    int m = tid & 127, th = tid >> 7;  // th in 0..1 -> 4 rows each
    float acc[4] = {};
#pragma unroll 8
    for (int d = 0; d < DIM; ++d) {
      float kv = K[d * DIM + m];  // coalesced, L2-resident
#pragma unroll
      for (int r = 0; r < 4; ++r)
        acc[r] = fmaf(xs[(th * 4 + r) * DIM + d], kv, acc[r]);
    }
#pragma unroll
    for (int r = 0; r < 4; ++r)  // sc1: read cross-XCD at out phase
      ST_A(&U[(tc * 8 + th * 4 + r) * BMROWS + b * DIM + m], acc[r]);
    if (blk == 0) ST_A(&P[tid], Bm[tid]);  // P[0][:] = b
    __syncthreads();  // before Slds reuse in chain
  }

  // ---------- chain: step k reads S=A^(2^k), writes S^2 and P doubling ----
  const int rg = blk >> 3, cg = blk & 7;  // 4 rows x 32 cols per block
  const int lane = tid & 63, q = tid >> 6;
  const int cl = lane & 7;                // col quad: cols 4*cl..+4
  const int pr = (lane >> 3) & 1;         // row-pair bit
  const int ir = lane >> 4;               // 0..3 K-subsplit
  for (int k = 0; k < 8; ++k) {
    const float* S = (k == 0) ? A : (ws + OFF_AP + (k - 1) * APSTRIDE);
    float* Snew = ws + OFF_AP + ((k < 7) ? k : 6) * APSTRIDE;  // unused k=7
    const int half = 1 << k;
    const int nsq = (k < 7) ? 4 : 0;
    const int ndb = (k == 7) ? 2 : (rg < half ? 1 : 0);
    const int nrows = nsq + ndb;

    // stage left rows into lsb[5][256]; zero-pad unused
#pragma unroll
    for (int s = 0; s < 5; ++s) {
      float v = 0.f;
      if (s < nsq) {
        v = S[(4 * rg + s) * ORD + tid];
      } else if (s - nsq < ndb) {
        int d = rg + 64 * (s - nsq);
        v = (k == 0) ? Bm[tid] : P[d * ORD + tid];  // write-once P rows
      }
      lsb[s * ORD + tid] = v;
    }
    // stage right slice S[:, 32cg..+32) into Slds[256][32] via float4
#pragma unroll
    for (int j = 0; j < 8; ++j) {
      int f = tid + 256 * j;
      int i = f >> 3, cc = (f & 7) * 4;
      *(float4*)&Slds[i * 32 + cc] =
          *(const float4*)&S[i * ORD + cg * 32 + cc];
    }
    __syncthreads();

    // wave q covers K-chunk [64q,64q+64); lane = (ir,pr K-split, cl cols)
    float acc[5][4] = {};
#pragma unroll 4
    for (int ii = 0; ii < 8; ++ii) {
      int i = q * 64 + ir * 16 + ii * 2 + pr;
      float4 sv = *(const float4*)&Slds[i * 32 + 4 * cl];  // 256B/16-lane phase
#pragma unroll
      for (int s = 0; s < 5; ++s) {
        float lv = lsb[s * ORD + i];  // broadcast
        acc[s][0] = fmaf(lv, sv.x, acc[s][0]);
        acc[s][1] = fmaf(lv, sv.y, acc[s][1]);
        acc[s][2] = fmaf(lv, sv.z, acc[s][2]);
        acc[s][3] = fmaf(lv, sv.w, acc[s][3]);
      }
    }
#pragma unroll
    for (int s = 0; s < 5; ++s)
#pragma unroll
      for (int w = 0; w < 4; ++w) {
        acc[s][w] += __shfl_xor(acc[s][w], 8);
        acc[s][w] += __shfl_xor(acc[s][w], 16);
        acc[s][w] += __shfl_xor(acc[s][w], 32);
      }
    if (lane < 8) {
#pragma unroll
      for (int s = 0; s < 5; ++s)
        *(float4*)&redb[q * 160 + s * 32 + 4 * cl] =
            make_float4(acc[s][0], acc[s][1], acc[s][2], acc[s][3]);
    }
    __syncthreads();
    if (tid < 160) {
      int s = tid >> 5, c = tid & 31;
      if (s < nrows) {
        float sum = redb[tid] + redb[160 + tid] + redb[320 + tid] +
                    redb[480 + tid];
        if (s < nsq) {
          ST_A(&Snew[(4 * rg + s) * ORD + cg * 32 + c], sum);
        } else {
          int d = rg + 64 * (s - nsq);
          ST_A(&P[(half + d) * ORD + cg * 32 + c], sum);
        }
      }
    }
    if (k < 7) gbar(flags, gen, (unsigned)(k + 1));
  }

  // ---------- round-7 ARRIVE (split gbar, target 8) ----------
  asm volatile("s_waitcnt vmcnt(0)" ::: "memory");  // drain P[128..255] sc1 st
  __syncthreads();  // all waves drained; lsb/redb reads done
  if (tid == 0) ST_A(&flags[blk], 8u);

  // ---------- out: out[bm][o] = sum_t U[t][bm] * P[255-t][o] ----------
  // pass 1 (t in [128,256)) reads P rows 0..127 (final since barrier 7);
  // pass 2 (t in [0,128)) reads rows 128..255 after the barrier completes.
  {
    float* us = lsb;     // [256][4]
    float* redo = Slds;  // [4][4][256] wave partials
    int bm0 = blk * 4;
    for (int idx = tid; idx < SEQ_T * 4; idx += 256) {
      int t = idx >> 2, r = idx & 3;
      us[idx] = U[t * BMROWS + bm0 + r];  // normal load: first touch of U
    }
    __syncthreads();
    int c4o = lane * 4, qo = q;
    float ao[4][4] = {};
    // pass 1: wave qo covers t = 128 + [32qo, 32qo+32)
#pragma unroll 4
    for (int tt = 0; tt < 32; ++tt) {
      int t = 128 + qo * 32 + tt;
      float4 pv = *(const float4*)&P[(SEQ_T - 1 - t) * ORD + c4o];  // L2-hot
      float4 uv = *(const float4*)&us[t * 4];  // LDS broadcast
      float u[4] = {uv.x, uv.y, uv.z, uv.w};
      float pw[4] = {pv.x, pv.y, pv.z, pv.w};
#pragma unroll
      for (int r = 0; r < 4; ++r)
#pragma unroll
        for (int w = 0; w < 4; ++w) ao[r][w] = fmaf(u[r], pw[w], ao[r][w]);
    }
    // ---------- complete final barrier (latency hidden under pass 1) ----
    if (blk == 0) {
      while (LD_A(&flags[tid]) < 8u || LD_A(&flags[tid + 256]) < 8u)
        __builtin_amdgcn_s_sleep(1);
      __syncthreads();  // all 512 flags seen
      if (tid == 0) ST_A(gen, 8u);
    } else {
      if (tid == 0)
        while (LD_A(gen) < 8u) __builtin_amdgcn_s_sleep(1);
    }
    __syncthreads();
    // pass 2: wave qo covers t = [32qo, 32qo+32); P rows 128..255 now final
#pragma unroll 4
    for (int tt = 0; tt < 32; ++tt) {
      int t = qo * 32 + tt;
      float4 pv = *(const float4*)&P[(SEQ_T - 1 - t) * ORD + c4o];
      float4 uv = *(const float4*)&us[t * 4];
      float u[4] = {uv.x, uv.y, uv.z, uv.w};
      float pw[4] = {pv.x, pv.y, pv.z, pv.w};
#pragma unroll
      for (int r = 0; r < 4; ++r)
#pragma unroll
        for (int w = 0; w < 4; ++w) ao[r][w] = fmaf(u[r], pw[w], ao[r][w]);
    }
#pragma unroll
    for (int r = 0; r < 4; ++r)
      *(float4*)&redo[qo * 1024 + r * 256 + c4o] =
          make_float4(ao[r][0], ao[r][1], ao[r][2], ao[r][3]);
    __syncthreads();
#pragma unroll
    for (int j = 0; j < 4; ++j) {
      int o = tid + 256 * j;  // o = r*256 + c
      float s = redo[o] + redo[1024 + o] + redo[2048 + o] + redo[3072 + o];
      out[bm0 * ORD + o] = s;  // kernel-end release flushes
    }
  }
}

extern "C" void kernel_launch(void* const* d_in, const int* in_sizes, int n_in,
                              void* d_out, int out_size, void* d_ws,
                              size_t ws_size, hipStream_t stream) {
  const float* x = (const float*)d_in[0];   // (16,256,128)
  const float* K = (const float*)d_in[1];   // (128,128)
  const float* A = (const float*)d_in[2];   // (256,256)
  const float* Bm = (const float*)d_in[3];  // (256,)
  float* out = (float*)d_out;               // (16, 32768)
  float* ws = (float*)d_ws;

  // zero barrier flags + gen (ws re-poisoned 0xAA before every timed call)
  hipMemsetAsync(ws + OFF_FLAGS, 0, 4096, stream);
  lrmu_all<<<NBLK, 256, 0, stream>>>(x, K, A, Bm, out, ws);
}